// Round 12
// baseline (164.701 us; speedup 1.0000x reference)
//
#include <hip/hip_runtime.h>

#define B_  8
#define C_  256
#define N_  16384
#define NM_ 128

typedef _Float16 f16x4 __attribute__((ext_vector_type(4)));
typedef _Float16 f16x8 __attribute__((ext_vector_type(8)));
typedef float    f32x4 __attribute__((ext_vector_type(4)));

#define MFMA16(A, Bf, Cc) __builtin_amdgcn_mfma_f32_16x16x16f16((A), (Bf), (Cc), 0, 0, 0)

// convert float4 -> hi f16x4 + lo f16x4 (scalar casts), accumulate squared norm
#define CVT4(V, HI, LO, SQ)                                            \
    {                                                                  \
        float el_[4] = {(V).x, (V).y, (V).z, (V).w};                   \
        _Pragma("unroll")                                              \
        for (int e_ = 0; e_ < 4; ++e_) {                               \
            float v_ = el_[e_];                                        \
            _Float16 h_ = (_Float16)v_;                                \
            (HI)[e_] = h_;                                             \
            (LO)[e_] = (_Float16)(v_ - (float)h_);                     \
            (SQ) += v_ * v_;                                           \
        }                                                              \
    }

// ---------------- kernel 1: split-K fp16x2 MFMA GEMM ----------------
// BM=128 x BN=256(full C) x BK=16. 512 threads = 8 waves (2 wm x 4 wn), wave tile 64x64,
// acc[4][4] f32x4 = 64 VGPR, 16x16x16 MFMA (f16x4 frags = half the fragment registers).
// Stage-convert ONCE per element (reg-stage fp32 -> hi/lo f16 -> LDS). LDS 48KB dbuf.
// Traffic: X read once, Y twice = 402 MB total. KS up to 32 -> grid 512 = 2 blocks/CU.
__global__ __launch_bounds__(512)
__attribute__((amdgpu_waves_per_eu(4, 4)))
void gemm_f16_kernel(const float* __restrict__ X,
                     const float* __restrict__ Y,
                     float* __restrict__ Gp,
                     float* __restrict__ x2p,
                     float* __restrict__ y2p,
                     int Kchunk) {
    __shared__ _Float16 aH[2][128][16];
    __shared__ _Float16 aL[2][128][16];
    __shared__ _Float16 bH[2][256][16];
    __shared__ _Float16 bL[2][256][16];

    // XCD-aware swizzle (grid = KS*16, multiple of 8)
    int cpx = gridDim.x >> 3;
    int lin = (blockIdx.x & 7) * cpx + (blockIdx.x >> 3);

    int it = lin & 1, b = (lin >> 1) & 7, ks = lin >> 4;
    int k0 = ks * Kchunk;
    int nsteps = Kchunk >> 4;   // BK=16

    int t = threadIdx.x;
    int lane = t & 63;
    int wid = t >> 6;                  // 0..7
    int wm = wid >> 2, wn = wid & 3;   // wave tile 64x64 at (wm*64, wn*64)
    int fr = lane & 15, ug = lane >> 4;

    // staging shares: A row t>>2 (0..127), k4 = (t&3)*4 ; B row t>>1 (0..255), k8 = (t&1)*8
    int ar = t >> 2, ak = (t & 3) * 4;
    int br = t >> 1, bk = (t & 1) * 8;
    const float* ax = X + (size_t)(b * C_ + it * 128 + ar) * N_ + k0 + ak;
    const float* by = Y + (size_t)(b * C_ + br) * N_ + k0 + bk;

    f32x4 acc[4][4] = {};
    float sx = 0.f, sy = 0.f;
    float4 vA, vB0, vB1;

    auto loads = [&](int i) {
        vA  = *(const float4*)(ax + i * 16);
        vB0 = *(const float4*)(by + i * 16);
        vB1 = *(const float4*)(by + i * 16 + 4);
    };
    auto convert_store = [&](int sl) {
        f16x4 hA, lA;
        CVT4(vA, hA, lA, sx);
        *(f16x4*)&aH[sl][ar][ak] = hA;
        *(f16x4*)&aL[sl][ar][ak] = lA;
        f16x4 h0, l0, h1, l1;
        CVT4(vB0, h0, l0, sy);
        CVT4(vB1, h1, l1, sy);
        f16x8 hb, lb;
#pragma unroll
        for (int e = 0; e < 4; ++e) { hb[e] = h0[e]; hb[e + 4] = h1[e]; lb[e] = l0[e]; lb[e + 4] = l1[e]; }
        *(f16x8*)&bH[sl][br][bk] = hb;
        *(f16x8*)&bL[sl][br][bk] = lb;
    };

    // prologue
    loads(0);
    convert_store(0);
    __syncthreads();

    for (int i = 0; i < nsteps; ++i) {
        int sl = i & 1;
        if (i + 1 < nsteps) loads(i + 1);     // issue early; lands during MFMA phase

        // fragments: f16x4 per 16x16 tile, lane: row fr, k = ug*4
        f16x4 aHi[4], aLo[4];
#pragma unroll
        for (int mf = 0; mf < 4; ++mf) {
            aHi[mf] = *(const f16x4*)&aH[sl][wm * 64 + mf * 16 + fr][ug * 4];
            aLo[mf] = *(const f16x4*)&aL[sl][wm * 64 + mf * 16 + fr][ug * 4];
        }
        __builtin_amdgcn_s_setprio(1);
#pragma unroll
        for (int nf = 0; nf < 4; ++nf) {
            f16x4 bHi = *(const f16x4*)&bH[sl][wn * 64 + nf * 16 + fr][ug * 4];
            f16x4 bLo = *(const f16x4*)&bL[sl][wn * 64 + nf * 16 + fr][ug * 4];
#pragma unroll
            for (int mf = 0; mf < 4; ++mf) {
                acc[mf][nf] = MFMA16(aHi[mf], bHi, acc[mf][nf]);
                acc[mf][nf] = MFMA16(aHi[mf], bLo, acc[mf][nf]);
                acc[mf][nf] = MFMA16(aLo[mf], bHi, acc[mf][nf]);
            }
        }
        __builtin_amdgcn_s_setprio(0);

        if (i + 1 < nsteps) convert_store(sl ^ 1);
        __syncthreads();
    }

    // norm partials: A row covered by 4 threads (t&3 k-slices); B row by 2 threads (t&1)
    sx += __shfl_xor(sx, 1);
    sx += __shfl_xor(sx, 2);
    if ((t & 3) == 0) x2p[(ks * B_ + b) * C_ + it * 128 + ar] = sx;
    sy += __shfl_xor(sy, 1);
    if (it == 0 && (t & 1) == 0) y2p[(ks * B_ + b) * C_ + br] = sy;

    // write G partial; C-layout: col = lane&15, row = (lane>>4)*4 + r
    size_t gbase = ((size_t)(ks * B_ + b) * C_ + it * 128) * C_;
#pragma unroll
    for (int mf = 0; mf < 4; ++mf)
#pragma unroll
        for (int nf = 0; nf < 4; ++nf) {
            int rr = wm * 64 + mf * 16 + (lane >> 4) * 4;
            int cc = wn * 64 + nf * 16 + (lane & 15);
#pragma unroll
            for (int r = 0; r < 4; ++r)
                Gp[gbase + (size_t)(rr + r) * C_ + cc] = acc[mf][nf][r];
        }
}

// ---------------- kernel 2: reduce split-K, d2 = x2+y2-2G, argmin over j (tie -> smaller j) ----------------
__global__ __launch_bounds__(256) void argmin_kernel(const float* __restrict__ Gp,
                                                     const float* __restrict__ x2p,
                                                     const float* __restrict__ y2p,
                                                     float* __restrict__ minval,
                                                     int* __restrict__ minidx,
                                                     int KS) {
    int bi = blockIdx.x;           // b*C + i
    int b = bi >> 8;
    int i = bi & 255;
    int j = threadIdx.x;           // 0..255 == C

    float g = 0.f, sx = 0.f, sy = 0.f;
    for (int ks = 0; ks < KS; ++ks) {
        g  += Gp[((size_t)(ks * B_ + b) * C_ + i) * C_ + j];
        sx += x2p[(ks * B_ + b) * C_ + i];
        sy += y2p[(ks * B_ + b) * C_ + j];
    }

    float v = sx + sy - 2.f * g;
    int idx = j;
#pragma unroll
    for (int off = 32; off > 0; off >>= 1) {
        float v2 = __shfl_down(v, off);
        int i2 = __shfl_down(idx, off);
        if (v2 < v || (v2 == v && i2 < idx)) { v = v2; idx = i2; }
    }
    __shared__ float wv[4];
    __shared__ int wi[4];
    int lane = threadIdx.x & 63, wid = threadIdx.x >> 6;
    if (lane == 0) { wv[wid] = v; wi[wid] = idx; }
    __syncthreads();
    if (threadIdx.x == 0) {
        for (int w = 1; w < 4; ++w)
            if (wv[w] < v || (wv[w] == v && wi[w] < idx)) { v = wv[w]; idx = wi[w]; }
        minval[bi] = v;
        minidx[bi] = idx;
    }
}

// ---------------- kernel 3: per-batch stable top-128 selection + compaction ----------------
__global__ __launch_bounds__(256) void select_kernel(const float* __restrict__ minval,
                                                     const int* __restrict__ minidx,
                                                     int* __restrict__ nn) {
    int b = blockIdx.x;
    int i = threadIdx.x;           // channel
    __shared__ float vals[C_];
    __shared__ int wcnt[4];

    float v = minval[b * C_ + i];
    vals[i] = v;
    __syncthreads();

    int rank = 0;
    for (int tt = 0; tt < C_; ++tt) {
        float u = vals[tt];
        rank += (u < v) || (u == v && tt < i);
    }
    bool flag = rank < NM_;

    unsigned long long m = __ballot(flag);
    int lane = i & 63, wid = i >> 6;
    if (lane == 0) wcnt[wid] = (int)__popcll(m);
    __syncthreads();
    int off = 0;
    for (int w = 0; w < wid; ++w) off += wcnt[w];
    int pos = off + (int)__popcll(m & ((1ULL << lane) - 1ULL));
    if (flag) nn[b * NM_ + pos] = minidx[b * C_ + i];
}

// ---------------- kernel 4: gather selected Ym rows ----------------
__global__ __launch_bounds__(256) void gather_kernel(const float* __restrict__ Y,
                                                     const int* __restrict__ nn,
                                                     float* __restrict__ out) {
    int blk = blockIdx.x;
    int b = blk >> 7;
    int m = blk & 127;
    int src = nn[b * NM_ + m];
    const float4* s = (const float4*)(Y + ((size_t)b * C_ + src) * N_);
    float4* d = (float4*)(out + ((size_t)b * NM_ + m) * N_);
    for (int tt = threadIdx.x; tt < N_ / 4; tt += 256) d[tt] = s[tt];
}

extern "C" void kernel_launch(void* const* d_in, const int* in_sizes, int n_in,
                              void* d_out, int out_size, void* d_ws, size_t ws_size,
                              hipStream_t stream) {
    const float* X = (const float*)d_in[0];
    const float* Y = (const float*)d_in[1];
    float* out = (float*)d_out;

    // choose split-K factor by available workspace (up to 32 for 2-blocks/CU occupancy)
    size_t favail = ws_size / 4;
    int KS = 1;
    while (KS < 32) {
        int KS2 = KS * 2;
        size_t need = (size_t)KS2 * B_ * C_ * C_          // Gp
                    + (size_t)KS2 * 2 * B_ * C_           // x2p, y2p
                    + 2 * B_ * C_ + B_ * NM_;             // minval/minidx/nn
        if (need > favail) break;
        KS = KS2;
    }
    int Kchunk = N_ / KS;

    float* minval = (float*)d_ws;
    int* minidx = (int*)(minval + B_ * C_);
    int* nn = minidx + B_ * C_;
    float* x2p = (float*)(nn + B_ * NM_);
    float* y2p = x2p + (size_t)KS * B_ * C_;
    float* Gp = y2p + (size_t)KS * B_ * C_;

    hipLaunchKernelGGL(gemm_f16_kernel, dim3(KS * 16), dim3(512), 0, stream, X, Y, Gp, x2p, y2p, Kchunk);
    hipLaunchKernelGGL(argmin_kernel, dim3(B_ * C_), dim3(256), 0, stream, Gp, x2p, y2p, minval, minidx, KS);
    hipLaunchKernelGGL(select_kernel, dim3(B_), dim3(256), 0, stream, minval, minidx, nn);
    hipLaunchKernelGGL(gather_kernel, dim3(B_ * NM_), dim3(256), 0, stream, Y, nn, out);
}